// Round 1
// baseline (2032.655 us; speedup 1.0000x reference)
//
#include <hip/hip_runtime.h>
#include <math.h>

#define NN 100000
#define EE 1600000
#define TT 4
#define NLQ 15
#define FDQ 3
#define HCQ 12
#define ENQ (EE + NN)          // 1700000 edges incl self-loops
#define SCAN_B 1024
#define NBQ ((NN + SCAN_B - 1) / SCAN_B)   // 98 blocks per t

// ---------------- stats: mean / 1/std (ddof=1) of requests[t, NL:] ----------------
__global__ void stats_kernel(const float* __restrict__ req, float* __restrict__ stats) {
    int t = blockIdx.x;
    const float* r = req + (size_t)t * NN;
    __shared__ float ssum[512], ssq[512];
    float s = 0.f, q = 0.f;
    for (int i = NLQ + threadIdx.x; i < NN; i += blockDim.x) {
        float v = r[i]; s += v; q += v * v;
    }
    ssum[threadIdx.x] = s; ssq[threadIdx.x] = q;
    __syncthreads();
    for (int off = blockDim.x >> 1; off > 0; off >>= 1) {
        if ((int)threadIdx.x < off) {
            ssum[threadIdx.x] += ssum[threadIdx.x + off];
            ssq[threadIdx.x]  += ssq[threadIdx.x + off];
        }
        __syncthreads();
    }
    if (threadIdx.x == 0) {
        float n = (float)(NN - NLQ);
        float mean = ssum[0] / n;
        float var  = (ssq[0] - ssum[0] * mean) / (n - 1.0f);
        stats[t * 2]     = mean;
        stats[t * 2 + 1] = 1.0f / sqrtf(var);
    }
}

// ---------------- CSR build ----------------
__global__ void hist_kernel(const int* __restrict__ ei, int* __restrict__ deg) {
    int id = blockIdx.x * blockDim.x + threadIdx.x;
    if (id >= TT * ENQ) return;
    int t = id / ENQ, e = id - t * ENQ;
    int dst = (e < EE) ? ei[(size_t)t * 2 * EE + EE + e] : (e - EE);
    atomicAdd(&deg[t * NN + dst], 1);
}

__global__ void scan_k1(const int* __restrict__ deg, int* __restrict__ tscan, int* __restrict__ bsum) {
    int t = blockIdx.y, b = blockIdx.x;
    int i = b * SCAN_B + threadIdx.x;
    __shared__ int sh[SCAN_B];
    int v = (i < NN) ? deg[t * NN + i] : 0;
    sh[threadIdx.x] = v;
    __syncthreads();
    for (int off = 1; off < SCAN_B; off <<= 1) {
        int x = sh[threadIdx.x];
        int y = ((int)threadIdx.x >= off) ? sh[threadIdx.x - off] : 0;
        __syncthreads();
        sh[threadIdx.x] = x + y;
        __syncthreads();
    }
    if (i < NN) tscan[t * NN + i] = sh[threadIdx.x];
    if (threadIdx.x == SCAN_B - 1) bsum[t * NBQ + b] = sh[threadIdx.x];
}

__global__ void scan_k2(int* __restrict__ bsum) {
    int t = blockIdx.x;
    if (threadIdx.x == 0) {
        int run = 0;
        for (int b = 0; b < NBQ; b++) {
            int v = bsum[t * NBQ + b];
            bsum[t * NBQ + b] = run;
            run += v;
        }
    }
}

__global__ void scan_k3(const int* __restrict__ tscan, const int* __restrict__ boff,
                        int* __restrict__ row_ptr, int* __restrict__ nextp) {
    int t = blockIdx.y;
    int i = blockIdx.x * SCAN_B + threadIdx.x;
    if (i >= NN) return;
    int excl = (i == 0) ? 0 : (tscan[t * NN + i - 1] + boff[t * NBQ + ((i - 1) >> 10)]);
    row_ptr[t * (NN + 1) + i] = excl;
    nextp[t * NN + i] = excl;
    if (i == NN - 1)
        row_ptr[t * (NN + 1) + NN] = tscan[t * NN + i] + boff[t * NBQ + (i >> 10)];
}

__global__ void fill_kernel(const int* __restrict__ ei, int* __restrict__ nextp, int* __restrict__ csr_src) {
    int id = blockIdx.x * blockDim.x + threadIdx.x;
    if (id >= TT * ENQ) return;
    int t = id / ENQ, e = id - t * ENQ;
    int src, dst;
    if (e < EE) {
        src = ei[(size_t)t * 2 * EE + e];
        dst = ei[(size_t)t * 2 * EE + EE + e];
    } else {
        src = dst = e - EE;
    }
    int pos = atomicAdd(&nextp[t * NN + dst], 1);
    csr_src[(size_t)t * ENQ + pos] = src;
}

// ---------------- layer-0 node kernel: build x (5 dims) inline, compute h, e_s, e_d ----------------
__global__ void node0_kernel(const int* __restrict__ nt, const float* __restrict__ req,
                             const float* __restrict__ ti, const float* __restrict__ emb,
                             const float* __restrict__ W, const float* __restrict__ as_,
                             const float* __restrict__ ad_, const float* __restrict__ stats,
                             float* __restrict__ h, float* __restrict__ es, float* __restrict__ ed) {
    __shared__ float sW[5 * HCQ], sas[HCQ], sad[HCQ];
    if (threadIdx.x < 5 * HCQ) sW[threadIdx.x] = W[threadIdx.x];
    if (threadIdx.x < HCQ) { sas[threadIdx.x] = as_[threadIdx.x]; sad[threadIdx.x] = ad_[threadIdx.x]; }
    __syncthreads();
    int id = blockIdx.x * blockDim.x + threadIdx.x;
    if (id >= TT * NN) return;
    int t = id / NN, n = id - t * NN;
    float mean = stats[t * 2], rstd = stats[t * 2 + 1];
    int typ = nt[id];
    float x[5];
    x[0] = emb[typ * FDQ + 0];
    x[1] = emb[typ * FDQ + 1];
    x[2] = emb[typ * FDQ + 2];
    float rv = req[id];
    x[3] = (n < NLQ) ? rv : (rv - mean) * rstd;
    x[4] = ti[id];
    float hv[HCQ];
#pragma unroll
    for (int c = 0; c < HCQ; c++) {
        float a = 0.f;
#pragma unroll
        for (int k = 0; k < 5; k++) a += x[k] * sW[k * HCQ + c];
        hv[c] = a;
    }
    float e0 = 0.f, e1 = 0.f, f0 = 0.f, f1 = 0.f;
#pragma unroll
    for (int c = 0; c < 6; c++) {
        e0 += hv[c] * sas[c];     f0 += hv[c] * sad[c];
        e1 += hv[6 + c] * sas[6 + c]; f1 += hv[6 + c] * sad[6 + c];
    }
#pragma unroll
    for (int c = 0; c < HCQ; c++) h[(size_t)id * HCQ + c] = hv[c];
    es[id * 2] = e0; es[id * 2 + 1] = e1;
    ed[id * 2] = f0; ed[id * 2 + 1] = f1;
}

// ---------------- layer-K node kernel (din = 12) ----------------
__global__ void nodeK_kernel(const float* __restrict__ x, const float* __restrict__ W,
                             const float* __restrict__ as_, const float* __restrict__ ad_,
                             float* __restrict__ h, float* __restrict__ es, float* __restrict__ ed) {
    __shared__ float sW[HCQ * HCQ], sas[HCQ], sad[HCQ];
    if (threadIdx.x < HCQ * HCQ) sW[threadIdx.x] = W[threadIdx.x];
    if (threadIdx.x < HCQ) { sas[threadIdx.x] = as_[threadIdx.x]; sad[threadIdx.x] = ad_[threadIdx.x]; }
    __syncthreads();
    int id = blockIdx.x * blockDim.x + threadIdx.x;
    if (id >= TT * NN) return;
    const float4* xp = (const float4*)(x + (size_t)id * HCQ);
    float4 xa = xp[0], xb = xp[1], xc = xp[2];
    float xv[HCQ] = { xa.x, xa.y, xa.z, xa.w, xb.x, xb.y, xb.z, xb.w, xc.x, xc.y, xc.z, xc.w };
    float hv[HCQ];
#pragma unroll
    for (int c = 0; c < HCQ; c++) {
        float a = 0.f;
#pragma unroll
        for (int k = 0; k < HCQ; k++) a += xv[k] * sW[k * HCQ + c];
        hv[c] = a;
    }
    float e0 = 0.f, e1 = 0.f, f0 = 0.f, f1 = 0.f;
#pragma unroll
    for (int c = 0; c < 6; c++) {
        e0 += hv[c] * sas[c];     f0 += hv[c] * sad[c];
        e1 += hv[6 + c] * sas[6 + c]; f1 += hv[6 + c] * sad[6 + c];
    }
#pragma unroll
    for (int c = 0; c < HCQ; c++) h[(size_t)id * HCQ + c] = hv[c];
    es[id * 2] = e0; es[id * 2 + 1] = e1;
    ed[id * 2] = f0; ed[id * 2 + 1] = f1;
}

// ---------------- fused edge pass: online softmax + weighted aggregation, per dst node ----------------
__global__ void edge_kernel(const int* __restrict__ row_ptr, const int* __restrict__ csr_src,
                            const float* __restrict__ h, const float* __restrict__ es,
                            const float* __restrict__ ed, const float* __restrict__ bias,
                            float* __restrict__ out, int do_relu) {
    __shared__ float sb[HCQ];
    if (threadIdx.x < HCQ) sb[threadIdx.x] = bias[threadIdx.x];
    __syncthreads();
    int id = blockIdx.x * blockDim.x + threadIdx.x;
    if (id >= TT * NN) return;
    int t = id / NN, n = id - t * NN;
    int beg = row_ptr[t * (NN + 1) + n];
    int end = row_ptr[t * (NN + 1) + n + 1];
    const int*   srcs = csr_src + (size_t)t * ENQ;
    const float* hb   = h  + (size_t)t * NN * HCQ;
    const float2* es2 = (const float2*)(es + (size_t)t * NN * 2);
    float ed0 = ed[id * 2], ed1 = ed[id * 2 + 1];
    float m0 = -INFINITY, m1 = -INFINITY, d0 = 0.f, d1 = 0.f;
    float acc[HCQ];
#pragma unroll
    for (int c = 0; c < HCQ; c++) acc[c] = 0.f;

    for (int e = beg; e < end; e++) {
        int s = srcs[e];
        float2 esv = es2[s];
        float l0 = esv.x + ed0; l0 = (l0 > 0.f) ? l0 : 0.2f * l0;
        float l1 = esv.y + ed1; l1 = (l1 > 0.f) ? l1 : 0.2f * l1;
        float nm0 = fmaxf(m0, l0), nm1 = fmaxf(m1, l1);
        float sc0 = __expf(m0 - nm0), sc1 = __expf(m1 - nm1);
        float w0  = __expf(l0 - nm0), w1  = __expf(l1 - nm1);
        m0 = nm0; m1 = nm1;
        d0 = d0 * sc0 + w0;
        d1 = d1 * sc1 + w1;
        const float4* hp = (const float4*)(hb + (size_t)s * HCQ);
        float4 ha = hp[0], hc = hp[1], he = hp[2];
        acc[0] = acc[0] * sc0 + w0 * ha.x;
        acc[1] = acc[1] * sc0 + w0 * ha.y;
        acc[2] = acc[2] * sc0 + w0 * ha.z;
        acc[3] = acc[3] * sc0 + w0 * ha.w;
        acc[4] = acc[4] * sc0 + w0 * hc.x;
        acc[5] = acc[5] * sc0 + w0 * hc.y;
        acc[6] = acc[6] * sc1 + w1 * hc.z;
        acc[7] = acc[7] * sc1 + w1 * hc.w;
        acc[8]  = acc[8]  * sc1 + w1 * he.x;
        acc[9]  = acc[9]  * sc1 + w1 * he.y;
        acc[10] = acc[10] * sc1 + w1 * he.z;
        acc[11] = acc[11] * sc1 + w1 * he.w;
    }
    float inv0 = 1.0f / (d0 + 1e-16f);
    float inv1 = 1.0f / (d1 + 1e-16f);
#pragma unroll
    for (int c = 0; c < HCQ; c++) {
        float v = acc[c] * ((c < 6) ? inv0 : inv1) + sb[c];
        if (do_relu) v = fmaxf(v, 0.f);
        out[(size_t)id * HCQ + c] = v;
    }
}

extern "C" void kernel_launch(void* const* d_in, const int* in_sizes, int n_in,
                              void* d_out, int out_size, void* d_ws, size_t ws_size,
                              hipStream_t stream) {
    const int*   nt  = (const int*)d_in[0];
    const float* req = (const float*)d_in[1];
    const float* ti  = (const float*)d_in[2];
    const int*   ei  = (const int*)d_in[3];
    const float* emb = (const float*)d_in[4];
    const float* W[4], *as_[4], *ad_[4], *bb[4];
    for (int l = 0; l < 4; l++) {
        W[l]   = (const float*)d_in[5 + l * 4 + 0];
        as_[l] = (const float*)d_in[5 + l * 4 + 1];
        ad_[l] = (const float*)d_in[5 + l * 4 + 2];
        bb[l]  = (const float*)d_in[5 + l * 4 + 3];
    }

    char* p = (char*)d_ws;
    auto alloc = [&](size_t bytes) -> void* {
        void* r = (void*)p;
        p += (bytes + 255) & ~(size_t)255;
        return r;
    };
    float* stats   = (float*)alloc((size_t)TT * 2 * 4);
    int*   deg     = (int*)  alloc((size_t)TT * NN * 4);
    int*   tscan   = (int*)  alloc((size_t)TT * NN * 4);
    int*   bsum    = (int*)  alloc((size_t)TT * NBQ * 4);
    int*   row_ptr = (int*)  alloc((size_t)TT * (NN + 1) * 4);
    int*   nextp   = (int*)  alloc((size_t)TT * NN * 4);
    int*   csr     = (int*)  alloc((size_t)TT * ENQ * 4);
    float* h       = (float*)alloc((size_t)TT * NN * HCQ * 4);
    float* es      = (float*)alloc((size_t)TT * NN * 2 * 4);
    float* ed      = (float*)alloc((size_t)TT * NN * 2 * 4);
    float* xbuf    = (float*)alloc((size_t)TT * NN * HCQ * 4);

    hipMemsetAsync(deg, 0, (size_t)TT * NN * 4, stream);

    stats_kernel<<<TT, 512, 0, stream>>>(req, stats);

    int egrid = (TT * ENQ + 255) / 256;
    hist_kernel<<<egrid, 256, 0, stream>>>(ei, deg);
    scan_k1<<<dim3(NBQ, TT), SCAN_B, 0, stream>>>(deg, tscan, bsum);
    scan_k2<<<TT, 64, 0, stream>>>(bsum);
    scan_k3<<<dim3(NBQ, TT), SCAN_B, 0, stream>>>(tscan, bsum, row_ptr, nextp);
    fill_kernel<<<egrid, 256, 0, stream>>>(ei, nextp, csr);

    int ngrid = (TT * NN + 255) / 256;
    node0_kernel<<<ngrid, 256, 0, stream>>>(nt, req, ti, emb, W[0], as_[0], ad_[0], stats, h, es, ed);
    edge_kernel<<<ngrid, 256, 0, stream>>>(row_ptr, csr, h, es, ed, bb[0], xbuf, 1);

    for (int l = 1; l <= 2; l++) {
        nodeK_kernel<<<ngrid, 256, 0, stream>>>(xbuf, W[l], as_[l], ad_[l], h, es, ed);
        edge_kernel<<<ngrid, 256, 0, stream>>>(row_ptr, csr, h, es, ed, bb[l], xbuf, 1);
    }
    nodeK_kernel<<<ngrid, 256, 0, stream>>>(xbuf, W[3], as_[3], ad_[3], h, es, ed);
    edge_kernel<<<ngrid, 256, 0, stream>>>(row_ptr, csr, h, es, ed, bb[3], (float*)d_out, 0);
}